// Round 2
// baseline (2044.408 us; speedup 1.0000x reference)
//
#include <hip/hip_runtime.h>
#include <hip/hip_bf16.h>
#include <math.h>

// GGNN: N=50000 nodes, E=400000 edges, G=64 graphs, IN=64, OUT=128, 4 etypes, 8 steps.
// R7: occupancy + O-table elimination.
//   hx[N][256] fp16: cols 0..127 = ab (aggregated msg), cols 128..255 = hb (h shadow).
//   k_agg_gemm (64-row tiles, grid 782): CSR gather of hb-half -> s_t in regs -> LDS
//     -> K=128 MFMA per etype, + cnt*bs epilogue -> ab-half of hx.
//   k_gates_gru (64-row tiles): one block computes ALL gates for its rows:
//     R = sigm([ab|hb]·[Wih_r|Whh_r]^T + bih_r+bhh_r)   (K=256)
//     Z = same for z                                     (K=256)
//     IN = ab·Wih_n^T + bih_n, HN = hb·Whh_n^T + bhh_n   (K=128 each)
//     GRU pointwise fully in-register (R/Z/IN/HN share lane/reg slots), writes h fp32
//     + hb-half of hx. O table (76.8 MB x2 per step) GONE; k_gru GONE.
//   Weights repacked once (k_pack) into K=256 rows + fused biases.

#define NN 50000
#define NE 400000
#define NG 64
#define IND 64
#define OD 128
#define NN4 (NN * 4)
#define RC 8      // readout chunks per graph

typedef _Float16 f16x8 __attribute__((ext_vector_type(8)));
typedef _Float16 f16x4 __attribute__((ext_vector_type(4)));
typedef _Float16 f16x2 __attribute__((ext_vector_type(2)));
typedef float f32x4 __attribute__((ext_vector_type(4)));

__device__ inline unsigned short f2h(float x) {
    _Float16 hv = (_Float16)x;
    unsigned short u;
    __builtin_memcpy(&u, &hv, 2);
    return u;
}

// ---------------- fp32 -> fp16 weight conversion (Ws only) ----------------
__global__ void k_cvt(const float* __restrict__ s, unsigned short* __restrict__ d, int n) {
    int i = blockIdx.x * 256 + threadIdx.x;
    if (i < n) d[i] = f2h(s[i]);
}

// ---------------- pack GRU weights: Wpk = [R(128x256) | Z(128x256) | IN(128x128) | HN(128x128)]
// R row o = [W_ih[o][:] | W_hh[o][:]], Z row o = [W_ih[128+o][:] | W_hh[128+o][:]]
// IN row o = W_ih[256+o][:], HN row o = W_hh[256+o][:]
// bpk[0..255] = b_ih+b_hh (r,z), bpk[256..383] = b_ih[256..], bpk[384..511] = b_hh[256..]
__global__ void k_pack(const float* __restrict__ Wih, const float* __restrict__ Whh,
                       const float* __restrict__ bih, const float* __restrict__ bhh,
                       unsigned short* __restrict__ Wpk, float* __restrict__ bpk) {
    int i = blockIdx.x * 256 + threadIdx.x;
    if (i < 65536) {                       // R,Z block: o 0..255, k 0..255
        int o = i >> 8, k = i & 255;
        float v = (k < 128) ? Wih[o * 128 + k] : Whh[o * 128 + (k - 128)];
        Wpk[i] = f2h(v);
    } else if (i < 98304) {                // IN,HN block
        int j = i - 65536;
        int o = j >> 7, k = j & 127;       // o 0..255: 0..127 IN, 128..255 HN
        float v = (o < 128) ? Wih[(256 + o) * 128 + k] : Whh[(256 + (o - 128)) * 128 + k];
        Wpk[i] = f2h(v);
    }
    if (i < 512) {
        float b;
        if (i < 256) b = bih[i] + bhh[i];
        else if (i < 384) b = bih[i];
        else b = bhh[i - 128];
        bpk[i] = b;
    }
}

// ---------------- init h = [node_features | 0] (fp32 + fp16 shadow in hx) -------------
__global__ void k_init_h(const float* __restrict__ nf, float* __restrict__ h,
                         unsigned short* __restrict__ hx) {
    int i = blockIdx.x * 256 + threadIdx.x;
    if (i >= NN * OD) return;
    int n = i >> 7, d = i & 127;
    float v = (d < IND) ? nf[n * IND + d] : 0.f;
    h[i] = v;
    hx[(size_t)n * 256 + 128 + d] = f2h(v);
}

// ---------------- (dst, etype) CSR build: 200000 segments ----------------
__global__ void k_count(const int* __restrict__ dst, const int* __restrict__ et,
                        int* __restrict__ deg4) {
    int e = blockIdx.x * 256 + threadIdx.x;
    if (e < NE) atomicAdd(&deg4[dst[e] * 4 + et[e]], 1);
}

__global__ void k_scan1(const int* __restrict__ deg, int* __restrict__ rowp,
                        int* __restrict__ bsum, int n) {
    __shared__ int buf[1024];
    int tid = threadIdx.x;
    int i = blockIdx.x * 1024 + tid;
    int v = (i < n) ? deg[i] : 0;
    buf[tid] = v;
    __syncthreads();
    for (int off = 1; off < 1024; off <<= 1) {
        int t = (tid >= off) ? buf[tid - off] : 0;
        __syncthreads();
        buf[tid] += t;
        __syncthreads();
    }
    if (i < n) rowp[i + 1] = buf[tid];
    if (tid == 1023) bsum[blockIdx.x] = buf[tid];
}

__global__ void k_scan2(int* __restrict__ bsum, int nb) {
    __shared__ int buf[256];
    int tid = threadIdx.x;
    int v = (tid < nb) ? bsum[tid] : 0;
    buf[tid] = v;
    __syncthreads();
    for (int off = 1; off < 256; off <<= 1) {
        int t = (tid >= off) ? buf[tid - off] : 0;
        __syncthreads();
        buf[tid] += t;
        __syncthreads();
    }
    if (tid < nb) bsum[tid] = buf[tid] - v;   // exclusive
}

__global__ void k_scan3(const int* __restrict__ deg, const int* __restrict__ bsum,
                        int* __restrict__ rowp, int* __restrict__ cursor, int n) {
    int i = blockIdx.x * 256 + threadIdx.x;
    if (i >= n) return;
    int incl = rowp[i + 1] + bsum[i >> 10];
    rowp[i + 1] = incl;
    cursor[i] = incl - deg[i];
    if (i == 0) rowp[0] = 0;
}

__global__ void k_fill(const int* __restrict__ src, const int* __restrict__ dst,
                       const int* __restrict__ et, int* __restrict__ cursor,
                       int* __restrict__ esrc) {
    int e = blockIdx.x * 256 + threadIdx.x;
    if (e < NE) {
        int pos = atomicAdd(&cursor[dst[e] * 4 + et[e]], 1);
        esrc[pos] = src[e];
    }
}

// ---------------- graph CSR build (by graph id), for readout ----------------
__global__ void k_gcount(const int* __restrict__ gid, int* __restrict__ gdeg) {
    __shared__ int c[NG];
    int tid = threadIdx.x;
    if (tid < NG) c[tid] = 0;
    __syncthreads();
    int n = blockIdx.x * 1024 + tid;
    if (n < NN) atomicAdd(&c[gid[n]], 1);
    __syncthreads();
    if (tid < NG && c[tid] > 0) atomicAdd(&gdeg[tid], c[tid]);
}

__global__ void k_gscan(const int* __restrict__ gdeg, int* __restrict__ growp,
                        int* __restrict__ gcur) {
    __shared__ int buf[NG];
    int tid = threadIdx.x;
    int v = gdeg[tid];
    buf[tid] = v;
    __syncthreads();
    for (int off = 1; off < NG; off <<= 1) {
        int t = (tid >= off) ? buf[tid - off] : 0;
        __syncthreads();
        buf[tid] += t;
        __syncthreads();
    }
    growp[tid + 1] = buf[tid];
    gcur[tid] = buf[tid] - v;
    if (tid == 0) growp[0] = 0;
}

__global__ void k_gfill(const int* __restrict__ gid, int* __restrict__ gcur,
                        int* __restrict__ nlist) {
    __shared__ int lcnt[NG];
    __shared__ int lbase[NG];
    int tid = threadIdx.x;
    if (tid < NG) lcnt[tid] = 0;
    __syncthreads();
    int n = blockIdx.x * 1024 + tid;
    int g = -1, rank = 0;
    if (n < NN) { g = gid[n]; rank = atomicAdd(&lcnt[g], 1); }
    __syncthreads();
    if (tid < NG && lcnt[tid] > 0) lbase[tid] = atomicAdd(&gcur[tid], lcnt[tid]);
    __syncthreads();
    if (n < NN) nlist[lbase[g] + rank] = n;
}

// ---------------- fused aggregate + K=512 GEMM -> ab (hx cols 0..127) ----------------
// Block: 256 thr (4 waves), tile 64 dst nodes (grid 782). Gather: 4 threads/row,
// 32 dims each, fp32 reg accumulation. Per etype: regs -> LDS fp16 -> MFMA (B from
// global/L1). Epilogue: + cnt[v][t]*bs[t], fp16 store into ab half of hx.
__global__ __launch_bounds__(256) void k_agg_gemm(
    const unsigned short* __restrict__ hx,    // read cols 128..255 (hb)
    const int* __restrict__ rowp4, const int* __restrict__ esrc,
    const int* __restrict__ deg4,
    const unsigned short* __restrict__ Wsb,   // 4 * 128*128 fp16 (out x in)
    const float* __restrict__ bs,             // 4 * 128 fp32
    unsigned short* __restrict__ hxw) {       // write cols 0..127 (ab)
    __shared__ unsigned short Ss[64 * 136];
    __shared__ float Bsb[512];

    const int tid = threadIdx.x;
    const int m0 = blockIdx.x * 64;

    Bsb[tid] = bs[tid];
    Bsb[tid + 256] = bs[tid + 256];

    const int r = tid >> 2;          // gather row 0..63
    const int hsel = tid & 3;        // 32-dim quarter
    const int n = m0 + r;

    const int lane = tid & 63;
    const int w = tid >> 6;
    const int lr = lane & 15;
    const int q = lane >> 4;

    f32x4 acc[8];
#pragma unroll
    for (int nt = 0; nt < 8; ++nt) acc[nt] = (f32x4){0.f, 0.f, 0.f, 0.f};

    for (int t = 0; t < 4; ++t) {
        float sacc[32];
#pragma unroll
        for (int j = 0; j < 32; ++j) sacc[j] = 0.f;
        if (n < NN) {
            int beg = rowp4[n * 4 + t], end = rowp4[n * 4 + t + 1];
            for (int i = beg; i < end; ++i) {
                const f16x8* row8 =
                    (const f16x8*)&hx[(size_t)esrc[i] * 256 + 128 + hsel * 32];
#pragma unroll
                for (int jj = 0; jj < 4; ++jj) {
                    f16x8 v = row8[jj];
#pragma unroll
                    for (int k = 0; k < 8; ++k) sacc[jj * 8 + k] += (float)v[k];
                }
            }
        }
        __syncthreads();   // prior t's MFMA reads of Ss complete
#pragma unroll
        for (int jj = 0; jj < 4; ++jj) {
            f16x8 hv;
#pragma unroll
            for (int k = 0; k < 8; ++k) hv[k] = (_Float16)sacc[jj * 8 + k];
            *(f16x8*)&Ss[r * 136 + hsel * 32 + jj * 8] = hv;
        }
        __syncthreads();

        const unsigned short* Wt = Wsb + t * 16384;
#pragma unroll
        for (int ks = 0; ks < 4; ++ks) {
            f16x8 af = *(const f16x8*)&Ss[(w * 16 + lr) * 136 + ks * 32 + q * 8];
#pragma unroll
            for (int nt = 0; nt < 8; ++nt) {
                f16x8 bf = *(const f16x8*)&Wt[(nt * 16 + lr) * 128 + ks * 32 + q * 8];
                acc[nt] = __builtin_amdgcn_mfma_f32_16x16x32_f16(af, bf, acc[nt], 0, 0, 0);
            }
        }
    }

    // epilogue: + sum_t cnt*bs, fp16 store into ab half
    int rowbase = m0 + w * 16 + q * 4;
#pragma unroll
    for (int rr = 0; rr < 4; ++rr) {
        int n2 = rowbase + rr;
        if (n2 < NN) {
            int4 c = *(const int4*)&deg4[n2 * 4];
            unsigned short* arow = hxw + (size_t)n2 * 256;
#pragma unroll
            for (int nt = 0; nt < 8; ++nt) {
                int col = nt * 16 + lr;
                float v = acc[nt][rr]
                        + c.x * Bsb[col] + c.y * Bsb[128 + col]
                        + c.z * Bsb[256 + col] + c.w * Bsb[384 + col];
                arow[col] = f2h(v);
            }
        }
    }
}

// ---------------- fused gates GEMM + GRU: all 4 gate blocks + pointwise --------------
// Block: 256 thr (4 waves), tile 64 rows. acc[0..7]=R, [8..15]=Z, [16..23]=IN,
// [24..31]=HN. K loop: ks 0..3 over ab chunk (R,Z,IN), ks 4..7 over hb chunk (R,Z,HN).
// Epilogue: GRU in-register, write h fp32 + hb half of hx.
__global__ __launch_bounds__(256) void k_gates_gru(
    const unsigned short* __restrict__ hx,
    const unsigned short* __restrict__ Wpk,   // packed: R|Z (256-K) then IN|HN (128-K)
    const float* __restrict__ bpk,            // 512 packed biases
    float* __restrict__ h,
    unsigned short* __restrict__ hxw) {
    __shared__ unsigned short As[2 * 64 * 136];   // chunk0 = ab, chunk1 = hb
    __shared__ float Bsb[512];

    const int tid = threadIdx.x;
    const int m0 = blockIdx.x * 64;

    Bsb[tid] = bpk[tid];
    Bsb[tid + 256] = bpk[tid + 256];

    const uint4* H4 = (const uint4*)hx;   // 32 uint4 per 256-half row
#pragma unroll
    for (int it = 0; it < 8; ++it) {
        int i = tid + it * 256;           // 0..2047
        int row = i >> 5, qq = i & 31;
        int nn = m0 + row;
        uint4 v = (nn < NN) ? H4[(size_t)nn * 32 + qq] : make_uint4(0u, 0u, 0u, 0u);
        *(uint4*)&As[(qq >> 4) * 8704 + row * 136 + (qq & 15) * 8] = v;
    }
    __syncthreads();

    const int lane = tid & 63;
    const int w = tid >> 6;
    const int lr = lane & 15;
    const int q = lane >> 4;

    f32x4 acc[32];
#pragma unroll
    for (int j = 0; j < 32; ++j) acc[j] = (f32x4){0.f, 0.f, 0.f, 0.f};

    const int arow = (w * 16 + lr) * 136;
    const int brow = nullptr == nullptr ? 0 : 0;
    (void)brow;

#pragma unroll
    for (int ks = 0; ks < 4; ++ks) {     // ab chunk: R, Z, IN
        f16x8 af = *(const f16x8*)&As[arow + ks * 32 + q * 8];
#pragma unroll
        for (int nt = 0; nt < 8; ++nt) {
            int wr = (nt * 16 + lr);
            f16x8 bfR = *(const f16x8*)&Wpk[wr * 256 + ks * 32 + q * 8];
            acc[nt] = __builtin_amdgcn_mfma_f32_16x16x32_f16(af, bfR, acc[nt], 0, 0, 0);
            f16x8 bfZ = *(const f16x8*)&Wpk[32768 + wr * 256 + ks * 32 + q * 8];
            acc[8 + nt] = __builtin_amdgcn_mfma_f32_16x16x32_f16(af, bfZ, acc[8 + nt], 0, 0, 0);
            f16x8 bfI = *(const f16x8*)&Wpk[65536 + wr * 128 + ks * 32 + q * 8];
            acc[16 + nt] = __builtin_amdgcn_mfma_f32_16x16x32_f16(af, bfI, acc[16 + nt], 0, 0, 0);
        }
    }
#pragma unroll
    for (int ks = 4; ks < 8; ++ks) {     // hb chunk: R, Z, HN
        f16x8 af = *(const f16x8*)&As[8704 + arow + (ks - 4) * 32 + q * 8];
#pragma unroll
        for (int nt = 0; nt < 8; ++nt) {
            int wr = (nt * 16 + lr);
            f16x8 bfR = *(const f16x8*)&Wpk[wr * 256 + ks * 32 + q * 8];
            acc[nt] = __builtin_amdgcn_mfma_f32_16x16x32_f16(af, bfR, acc[nt], 0, 0, 0);
            f16x8 bfZ = *(const f16x8*)&Wpk[32768 + wr * 256 + ks * 32 + q * 8];
            acc[8 + nt] = __builtin_amdgcn_mfma_f32_16x16x32_f16(af, bfZ, acc[8 + nt], 0, 0, 0);
            f16x8 bfH = *(const f16x8*)&Wpk[81920 + wr * 128 + (ks - 4) * 32 + q * 8];
            acc[24 + nt] = __builtin_amdgcn_mfma_f32_16x16x32_f16(af, bfH, acc[24 + nt], 0, 0, 0);
        }
    }

    // GRU pointwise in-register
    int rowbase = m0 + w * 16 + q * 4;
#pragma unroll
    for (int rr = 0; rr < 4; ++rr) {
        int n2 = rowbase + rr;
        if (n2 < NN) {
            float* hrow = h + (size_t)n2 * OD;
            unsigned short* hxrow = hxw + (size_t)n2 * 256 + 128;
#pragma unroll
            for (int nt = 0; nt < 8; ++nt) {
                int col = nt * 16 + lr;
                float R = 1.f / (1.f + __expf(-(acc[nt][rr] + Bsb[col])));
                float Z = 1.f / (1.f + __expf(-(acc[8 + nt][rr] + Bsb[128 + col])));
                float NV = tanhf(acc[16 + nt][rr] + Bsb[256 + col]
                                 + R * (acc[24 + nt][rr] + Bsb[384 + col]));
                float hold = hrow[col];
                float hnew = (1.f - Z) * NV + Z * hold;
                hrow[col] = hnew;
                hxrow[col] = f2h(hnew);
            }
        }
    }
}

// ---------------- graph readout: register acc over graph-sorted node list ------------
__global__ void k_readout(const float* __restrict__ h, const float* __restrict__ nf,
                          const int* __restrict__ nlist, const int* __restrict__ growp,
                          float* __restrict__ partial) {
    int g = blockIdx.x >> 3, c = blockIdx.x & (RC - 1);
    int d = threadIdx.x;
    int s = growp[g], e = growp[g + 1], len = e - s;
    int i0 = s + (int)((long long)len * c / RC);
    int i1 = s + (int)((long long)len * (c + 1) / RC);
    float acc = 0.f;
    for (int i = i0; i < i1; ++i) {
        int n = nlist[i];
        acc += (d < OD) ? h[(size_t)n * OD + d] : nf[(size_t)n * IND + (d - OD)];
    }
    partial[(size_t)blockIdx.x * 192 + d] = acc;
}

__global__ void k_reduce(const float* __restrict__ partial, float* __restrict__ feats) {
    int i = blockIdx.x * 256 + threadIdx.x;
    if (i >= NG * 192) return;
    int g = i / 192, d = i % 192;
    float s = 0.f;
    for (int c = 0; c < RC; ++c) s += partial[(size_t)(g * RC + c) * 192 + d];
    feats[i] = s;
}

__global__ void k_final(const float* __restrict__ feats, const float* __restrict__ W_cls,
                        const float* __restrict__ b_cls, float* __restrict__ out) {
    int g = threadIdx.x;
    if (g >= NG) return;
    float acc = b_cls[0];
    for (int d = 0; d < 192; ++d) acc += feats[g * 192 + d] * W_cls[d];
    out[g] = 1.f / (1.f + __expf(-acc));
}

extern "C" void kernel_launch(void* const* d_in, const int* in_sizes, int n_in,
                              void* d_out, int out_size, void* d_ws, size_t ws_size,
                              hipStream_t stream) {
    const float* nf    = (const float*)d_in[0];
    const int*   src   = (const int*)d_in[1];
    const int*   dst   = (const int*)d_in[2];
    const int*   et    = (const int*)d_in[3];
    const int*   gid   = (const int*)d_in[4];
    const float* Ws    = (const float*)d_in[5];
    const float* bs    = (const float*)d_in[6];
    const float* W_ih  = (const float*)d_in[7];
    const float* W_hh  = (const float*)d_in[8];
    const float* b_ih  = (const float*)d_in[9];
    const float* b_hh  = (const float*)d_in[10];
    const float* W_cls = (const float*)d_in[11];
    const float* b_cls = (const float*)d_in[12];
    float* out = (float*)d_out;

    char* ws = (char*)d_ws;
    size_t off = 0;
    auto alloc = [&](size_t bytes) -> void* {
        off = (off + 255) & ~(size_t)255;
        void* p = ws + off;
        off += bytes;
        return p;
    };
    float*          h    = (float*)alloc((size_t)NN * OD * 4);              // 25.6 MB
    unsigned short* hx   = (unsigned short*)alloc((size_t)NN * 256 * 2);    // 25.6 MB
    int*   deg4    = (int*)alloc((size_t)NN4 * 4);
    int*   rowp4   = (int*)alloc((size_t)(NN4 + 1) * 4);
    int*   cursor4 = (int*)alloc((size_t)NN4 * 4);
    int*   esrc    = (int*)alloc((size_t)NE * 4);
    int*   bsum    = (int*)alloc(256 * 4);
    int*   gdeg    = (int*)alloc(NG * 4);
    int*   growp   = (int*)alloc((NG + 1) * 4);
    int*   gcur    = (int*)alloc(NG * 4);
    int*   nlist   = (int*)alloc((size_t)NN * 4);
    float* feats   = (float*)alloc((size_t)NG * 192 * 4);
    float* partial = (float*)alloc((size_t)NG * RC * 192 * 4);              // 393 KB
    unsigned short* wsb = (unsigned short*)alloc((size_t)4 * 16384 * 2);
    unsigned short* Wpk = (unsigned short*)alloc((size_t)98304 * 2);
    float*          bpk = (float*)alloc(512 * 4);
    (void)ws_size; (void)in_sizes; (void)n_in; (void)out_size;

    hipMemsetAsync(deg4, 0, (size_t)NN4 * 4, stream);
    hipMemsetAsync(gdeg, 0, NG * 4, stream);

    k_cvt<<<(4 * 16384 + 255) / 256, 256, 0, stream>>>(Ws, wsb, 4 * 16384);
    k_pack<<<(98304 + 255) / 256, 256, 0, stream>>>(W_ih, W_hh, b_ih, b_hh, Wpk, bpk);

    k_init_h<<<(NN * OD + 255) / 256, 256, 0, stream>>>(nf, h, hx);

    // (dst, etype) CSR
    k_count<<<(NE + 255) / 256, 256, 0, stream>>>(dst, et, deg4);
    const int nb4 = (NN4 + 1023) / 1024;   // 196
    k_scan1<<<nb4, 1024, 0, stream>>>(deg4, rowp4, bsum, NN4);
    k_scan2<<<1, 256, 0, stream>>>(bsum, nb4);
    k_scan3<<<(NN4 + 255) / 256, 256, 0, stream>>>(deg4, bsum, rowp4, cursor4, NN4);
    k_fill<<<(NE + 255) / 256, 256, 0, stream>>>(src, dst, et, cursor4, esrc);

    // graph CSR (readout)
    const int nbn = (NN + 1023) / 1024;    // 49
    k_gcount<<<nbn, 1024, 0, stream>>>(gid, gdeg);
    k_gscan<<<1, NG, 0, stream>>>(gdeg, growp, gcur);
    k_gfill<<<nbn, 1024, 0, stream>>>(gid, gcur, nlist);

    const int mt64 = (NN + 63) / 64;   // 782 node tiles
    for (int s = 0; s < 8; ++s) {
        k_agg_gemm<<<mt64, 256, 0, stream>>>(hx, rowp4, esrc, deg4, wsb, bs, hx);
        k_gates_gru<<<mt64, 256, 0, stream>>>(hx, Wpk, bpk, h, hx);
    }

    k_readout<<<NG * RC, 192, 0, stream>>>(h, nf, nlist, growp, partial);
    k_reduce<<<(NG * 192 + 255) / 256, 256, 0, stream>>>(partial, feats);
    k_final<<<1, 64, 0, stream>>>(feats, W_cls, b_cls, out);
}

// Round 3
// 1514.444 us; speedup vs baseline: 1.3499x; 1.3499x over previous
//
#include <hip/hip_runtime.h>
#include <hip/hip_bf16.h>
#include <math.h>

// GGNN: N=50000 nodes, E=400000 edges, G=64 graphs, IN=64, OUT=128, 4 etypes, 8 steps.
// R8: occupancy fix for the fused kernels.
//   hx[N][256] fp16: cols 0..127 = ab (aggregated msg), cols 128..255 = hb (h shadow).
//   k_agg_gemm: 512 thr / 64 rows; gather 8 dims/thread (sacc[16]); double-buffered Ss
//     -> 4 barriers/block; MFMA split (row-tile, 4 col-tiles) per wave (acc 16 f32x4).
//   k_gates_gru: 512 thr / 64 rows; wave (rg,g) computes gate g for 32 rows
//     (acc 16 f32x4 = 64 VGPR, vs R7's 128 which collapsed occupancy to 9%).
//     Gates exchanged via LDS fp16 (R,Z post-sigmoid; IN,HN pre-tanh), GRU pointwise
//     by all 512 threads, writes h fp32 + hb half. No O table; 65+90 MB/step total.

#define NN 50000
#define NE 400000
#define NG 64
#define IND 64
#define OD 128
#define NN4 (NN * 4)
#define RC 8      // readout chunks per graph

typedef _Float16 f16x8 __attribute__((ext_vector_type(8)));
typedef _Float16 f16x4 __attribute__((ext_vector_type(4)));
typedef _Float16 f16x2 __attribute__((ext_vector_type(2)));
typedef float f32x4 __attribute__((ext_vector_type(4)));

__device__ inline unsigned short f2h(float x) {
    _Float16 hv = (_Float16)x;
    unsigned short u;
    __builtin_memcpy(&u, &hv, 2);
    return u;
}

// ---------------- fp32 -> fp16 weight conversion (Ws only) ----------------
__global__ void k_cvt(const float* __restrict__ s, unsigned short* __restrict__ d, int n) {
    int i = blockIdx.x * 256 + threadIdx.x;
    if (i < n) d[i] = f2h(s[i]);
}

// ---------------- pack GRU weights ----------------
// Wpk = [R(128x256) | Z(128x256) | IN(128x128) | HN(128x128)] (halfs)
// R row o = [W_ih[o][:] | W_hh[o][:]], Z row o = [W_ih[128+o][:] | W_hh[128+o][:]]
// IN row o = W_ih[256+o][:], HN row o = W_hh[256+o][:]
// bpk[0..255] = b_ih+b_hh (r,z), bpk[256..383] = b_ih[256..], bpk[384..511] = b_hh[256..]
__global__ void k_pack(const float* __restrict__ Wih, const float* __restrict__ Whh,
                       const float* __restrict__ bih, const float* __restrict__ bhh,
                       unsigned short* __restrict__ Wpk, float* __restrict__ bpk) {
    int i = blockIdx.x * 256 + threadIdx.x;
    if (i < 65536) {                       // R,Z block: o 0..255, k 0..255
        int o = i >> 8, k = i & 255;
        float v = (k < 128) ? Wih[o * 128 + k] : Whh[o * 128 + (k - 128)];
        Wpk[i] = f2h(v);
    } else if (i < 98304) {                // IN,HN block
        int j = i - 65536;
        int o = j >> 7, k = j & 127;       // o 0..255: 0..127 IN, 128..255 HN
        float v = (o < 128) ? Wih[(256 + o) * 128 + k] : Whh[(256 + (o - 128)) * 128 + k];
        Wpk[i] = f2h(v);
    }
    if (i < 512) {
        float b;
        if (i < 256) b = bih[i] + bhh[i];
        else if (i < 384) b = bih[i];
        else b = bhh[i - 128];
        bpk[i] = b;
    }
}

// ---------------- init h = [node_features | 0] (fp32 + fp16 shadow in hx) -------------
__global__ void k_init_h(const float* __restrict__ nf, float* __restrict__ h,
                         unsigned short* __restrict__ hx) {
    int i = blockIdx.x * 256 + threadIdx.x;
    if (i >= NN * OD) return;
    int n = i >> 7, d = i & 127;
    float v = (d < IND) ? nf[n * IND + d] : 0.f;
    h[i] = v;
    hx[(size_t)n * 256 + 128 + d] = f2h(v);
}

// ---------------- (dst, etype) CSR build: 200000 segments ----------------
__global__ void k_count(const int* __restrict__ dst, const int* __restrict__ et,
                        int* __restrict__ deg4) {
    int e = blockIdx.x * 256 + threadIdx.x;
    if (e < NE) atomicAdd(&deg4[dst[e] * 4 + et[e]], 1);
}

__global__ void k_scan1(const int* __restrict__ deg, int* __restrict__ rowp,
                        int* __restrict__ bsum, int n) {
    __shared__ int buf[1024];
    int tid = threadIdx.x;
    int i = blockIdx.x * 1024 + tid;
    int v = (i < n) ? deg[i] : 0;
    buf[tid] = v;
    __syncthreads();
    for (int off = 1; off < 1024; off <<= 1) {
        int t = (tid >= off) ? buf[tid - off] : 0;
        __syncthreads();
        buf[tid] += t;
        __syncthreads();
    }
    if (i < n) rowp[i + 1] = buf[tid];
    if (tid == 1023) bsum[blockIdx.x] = buf[tid];
}

__global__ void k_scan2(int* __restrict__ bsum, int nb) {
    __shared__ int buf[256];
    int tid = threadIdx.x;
    int v = (tid < nb) ? bsum[tid] : 0;
    buf[tid] = v;
    __syncthreads();
    for (int off = 1; off < 256; off <<= 1) {
        int t = (tid >= off) ? buf[tid - off] : 0;
        __syncthreads();
        buf[tid] += t;
        __syncthreads();
    }
    if (tid < nb) bsum[tid] = buf[tid] - v;   // exclusive
}

__global__ void k_scan3(const int* __restrict__ deg, const int* __restrict__ bsum,
                        int* __restrict__ rowp, int* __restrict__ cursor, int n) {
    int i = blockIdx.x * 256 + threadIdx.x;
    if (i >= n) return;
    int incl = rowp[i + 1] + bsum[i >> 10];
    rowp[i + 1] = incl;
    cursor[i] = incl - deg[i];
    if (i == 0) rowp[0] = 0;
}

__global__ void k_fill(const int* __restrict__ src, const int* __restrict__ dst,
                       const int* __restrict__ et, int* __restrict__ cursor,
                       int* __restrict__ esrc) {
    int e = blockIdx.x * 256 + threadIdx.x;
    if (e < NE) {
        int pos = atomicAdd(&cursor[dst[e] * 4 + et[e]], 1);
        esrc[pos] = src[e];
    }
}

// ---------------- graph CSR build (by graph id), for readout ----------------
__global__ void k_gcount(const int* __restrict__ gid, int* __restrict__ gdeg) {
    __shared__ int c[NG];
    int tid = threadIdx.x;
    if (tid < NG) c[tid] = 0;
    __syncthreads();
    int n = blockIdx.x * 1024 + tid;
    if (n < NN) atomicAdd(&c[gid[n]], 1);
    __syncthreads();
    if (tid < NG && c[tid] > 0) atomicAdd(&gdeg[tid], c[tid]);
}

__global__ void k_gscan(const int* __restrict__ gdeg, int* __restrict__ growp,
                        int* __restrict__ gcur) {
    __shared__ int buf[NG];
    int tid = threadIdx.x;
    int v = gdeg[tid];
    buf[tid] = v;
    __syncthreads();
    for (int off = 1; off < NG; off <<= 1) {
        int t = (tid >= off) ? buf[tid - off] : 0;
        __syncthreads();
        buf[tid] += t;
        __syncthreads();
    }
    growp[tid + 1] = buf[tid];
    gcur[tid] = buf[tid] - v;
    if (tid == 0) growp[0] = 0;
}

__global__ void k_gfill(const int* __restrict__ gid, int* __restrict__ gcur,
                        int* __restrict__ nlist) {
    __shared__ int lcnt[NG];
    __shared__ int lbase[NG];
    int tid = threadIdx.x;
    if (tid < NG) lcnt[tid] = 0;
    __syncthreads();
    int n = blockIdx.x * 1024 + tid;
    int g = -1, rank = 0;
    if (n < NN) { g = gid[n]; rank = atomicAdd(&lcnt[g], 1); }
    __syncthreads();
    if (tid < NG && lcnt[tid] > 0) lbase[tid] = atomicAdd(&gcur[tid], lcnt[tid]);
    __syncthreads();
    if (n < NN) nlist[lbase[g] + rank] = n;
}

// ---------------- fused aggregate + K=512 GEMM -> ab (hx cols 0..127) ----------------
// 512 thr (8 waves), 64 dst rows. Gather: 8 threads/row (16 dims each, sacc[16]).
// Double-buffered Ss -> one barrier per etype. MFMA: wave w -> row-tile w>>1,
// col-tiles (w&1)*4..+4, acc 4 f32x4. Epilogue: + cnt[v][t]*bs[t] -> ab half of hx.
__global__ __launch_bounds__(512) void k_agg_gemm(
    const unsigned short* __restrict__ hx,    // read cols 128..255 (hb)
    const int* __restrict__ rowp4, const int* __restrict__ esrc,
    const int* __restrict__ deg4,
    const unsigned short* __restrict__ Wsb,   // 4 * 128*128 fp16 (out x in)
    const float* __restrict__ bs,             // 4 * 128 fp32
    unsigned short* __restrict__ hxw) {       // write cols 0..127 (ab)
    __shared__ unsigned short Ss[2][64 * 136];
    __shared__ float Bsb[512];

    const int tid = threadIdx.x;
    const int m0 = blockIdx.x * 64;

    Bsb[tid] = bs[tid];

    const int r = tid >> 3;          // gather row 0..63
    const int hsel = tid & 7;        // 16-dim slice
    const int n = m0 + r;

    const int lane = tid & 63;
    const int w = tid >> 6;          // wave 0..7
    const int lr = lane & 15;
    const int q = lane >> 4;
    const int rt = w >> 1;           // row-tile 0..3
    const int ntb = (w & 1) * 4;     // col-tile base

    f32x4 acc[4];
#pragma unroll
    for (int j = 0; j < 4; ++j) acc[j] = (f32x4){0.f, 0.f, 0.f, 0.f};

    for (int t = 0; t < 4; ++t) {
        float sacc[16];
#pragma unroll
        for (int j = 0; j < 16; ++j) sacc[j] = 0.f;
        if (n < NN) {
            int beg = rowp4[n * 4 + t], end = rowp4[n * 4 + t + 1];
            for (int i = beg; i < end; ++i) {
                const f16x8* row8 =
                    (const f16x8*)&hx[(size_t)esrc[i] * 256 + 128 + hsel * 16];
                f16x8 v0 = row8[0], v1 = row8[1];
#pragma unroll
                for (int k = 0; k < 8; ++k) {
                    sacc[k] += (float)v0[k];
                    sacc[8 + k] += (float)v1[k];
                }
            }
        }
        unsigned short* sb = &Ss[t & 1][0];
        {
            f16x8 h0, h1;
#pragma unroll
            for (int k = 0; k < 8; ++k) {
                h0[k] = (_Float16)sacc[k];
                h1[k] = (_Float16)sacc[8 + k];
            }
            *(f16x8*)&sb[r * 136 + hsel * 16] = h0;
            *(f16x8*)&sb[r * 136 + hsel * 16 + 8] = h1;
        }
        __syncthreads();   // Ss[t&1] writes visible; prior-prior reads done (see note)

        const unsigned short* Wt = Wsb + t * 16384;
#pragma unroll
        for (int ks = 0; ks < 4; ++ks) {
            f16x8 af = *(const f16x8*)&sb[(rt * 16 + lr) * 136 + ks * 32 + q * 8];
#pragma unroll
            for (int j = 0; j < 4; ++j) {
                int nt = ntb + j;
                f16x8 bf = *(const f16x8*)&Wt[(nt * 16 + lr) * 128 + ks * 32 + q * 8];
                acc[j] = __builtin_amdgcn_mfma_f32_16x16x32_f16(af, bf, acc[j], 0, 0, 0);
            }
        }
    }

    // epilogue: + sum_t cnt*bs, fp16 store into ab half
    int rowbase = m0 + rt * 16 + q * 4;
#pragma unroll
    for (int rr = 0; rr < 4; ++rr) {
        int n2 = rowbase + rr;
        if (n2 < NN) {
            int4 c = *(const int4*)&deg4[n2 * 4];
            unsigned short* arow = hxw + (size_t)n2 * 256;
#pragma unroll
            for (int j = 0; j < 4; ++j) {
                int col = (ntb + j) * 16 + lr;
                float v = acc[j][rr]
                        + c.x * Bsb[col] + c.y * Bsb[128 + col]
                        + c.z * Bsb[256 + col] + c.w * Bsb[384 + col];
                arow[col] = f2h(v);
            }
        }
    }
}

// ---------------- fused gates GEMM + GRU (512 thr, 64 rows) --------------------------
// Wave (rg = w>>2, g = w&3): gate g for rows rg*32..rg*32+31 -> acc[2][8] (64 VGPR).
// g=0:R (K=256), 1:Z (K=256), 2:IN (K=128, ab), 3:HN (K=128, hb).
// Gates -> LDS fp16 (R,Z post-sigmoid; IN,HN pre-tanh, biases folded), then all 512
// threads do GRU pointwise (16 elems each), write h fp32 + hb half of hx.
__global__ __launch_bounds__(512) void k_gates_gru(
    const unsigned short* __restrict__ hx,
    const unsigned short* __restrict__ Wpk,   // packed: R|Z (256-K) then IN|HN (128-K)
    const float* __restrict__ bpk,            // 512 packed biases
    float* __restrict__ h,
    unsigned short* __restrict__ hxw) {
    // union: phase 1 = As[2][64][136] (17408 halfs); phase 2 = G[4][64][136] (34816)
    __shared__ unsigned short LS[4 * 64 * 136];
    __shared__ float Bsb[512];

    const int tid = threadIdx.x;
    const int m0 = blockIdx.x * 64;

    Bsb[tid] = bpk[tid];

    const uint4* H4 = (const uint4*)hx;   // 32 uint4 per 256-half row
#pragma unroll
    for (int it = 0; it < 4; ++it) {
        int i = tid + it * 512;           // 0..2047
        int row = i >> 5, qq = i & 31;
        int nn = m0 + row;
        uint4 v = (nn < NN) ? H4[(size_t)nn * 32 + qq] : make_uint4(0u, 0u, 0u, 0u);
        *(uint4*)&LS[(qq >> 4) * 8704 + row * 136 + (qq & 15) * 8] = v;
    }
    __syncthreads();

    const int lane = tid & 63;
    const int w = tid >> 6;
    const int lr = lane & 15;
    const int q = lane >> 4;
    const int rg = w >> 2;       // row-group 0..1 (32 rows)
    const int g = w & 3;         // gate: 0=R 1=Z 2=IN 3=HN

    f32x4 acc[2][8];
#pragma unroll
    for (int rt = 0; rt < 2; ++rt)
#pragma unroll
        for (int nt = 0; nt < 8; ++nt) acc[rt][nt] = (f32x4){0.f, 0.f, 0.f, 0.f};

    if (g < 2) {   // R / Z: K=256 over [ab|hb]
        const unsigned short* Wg = Wpk + g * 32768;
#pragma unroll
        for (int ks = 0; ks < 8; ++ks) {
            int chunk = ks >> 2, ksl = ks & 3;
            f16x8 af[2];
#pragma unroll
            for (int rt = 0; rt < 2; ++rt)
                af[rt] = *(const f16x8*)&LS[chunk * 8704
                         + (rg * 32 + rt * 16 + lr) * 136 + ksl * 32 + q * 8];
#pragma unroll
            for (int nt = 0; nt < 8; ++nt) {
                f16x8 bf = *(const f16x8*)&Wg[(nt * 16 + lr) * 256 + ks * 32 + q * 8];
                acc[0][nt] = __builtin_amdgcn_mfma_f32_16x16x32_f16(af[0], bf, acc[0][nt], 0, 0, 0);
                acc[1][nt] = __builtin_amdgcn_mfma_f32_16x16x32_f16(af[1], bf, acc[1][nt], 0, 0, 0);
            }
        }
    } else {       // IN (chunk 0) / HN (chunk 1): K=128
        const int chunk = g - 2;
        const unsigned short* Wg = Wpk + 65536 + chunk * 16384;
#pragma unroll
        for (int ks = 0; ks < 4; ++ks) {
            f16x8 af[2];
#pragma unroll
            for (int rt = 0; rt < 2; ++rt)
                af[rt] = *(const f16x8*)&LS[chunk * 8704
                         + (rg * 32 + rt * 16 + lr) * 136 + ks * 32 + q * 8];
#pragma unroll
            for (int nt = 0; nt < 8; ++nt) {
                f16x8 bf = *(const f16x8*)&Wg[(nt * 16 + lr) * 128 + ks * 32 + q * 8];
                acc[0][nt] = __builtin_amdgcn_mfma_f32_16x16x32_f16(af[0], bf, acc[0][nt], 0, 0, 0);
                acc[1][nt] = __builtin_amdgcn_mfma_f32_16x16x32_f16(af[1], bf, acc[1][nt], 0, 0, 0);
            }
        }
    }
    __syncthreads();   // all MFMA done; As region dead, reuse LS for gates

    // store gate tile to LDS (fp16), bias folded; sigmoid for R/Z
    {
        const int gb = g * 8704;
        const int bofs = g * 128;
#pragma unroll
        for (int rt = 0; rt < 2; ++rt) {
            int rowb = rg * 32 + rt * 16 + q * 4;
#pragma unroll
            for (int rr = 0; rr < 4; ++rr) {
                int row = rowb + rr;
#pragma unroll
                for (int nt = 0; nt < 8; ++nt) {
                    int col = nt * 16 + lr;
                    float v = acc[rt][nt][rr] + Bsb[bofs + col];
                    if (g < 2) v = 1.f / (1.f + __expf(-v));
                    LS[gb + row * 136 + col] = f2h(v);
                }
            }
        }
    }
    __syncthreads();

    // GRU pointwise: thread -> (row = tid>>3, cols (tid&7)*16 .. +16)
    {
        int row = tid >> 3;
        int c0 = (tid & 7) * 16;
        int n2 = m0 + row;
        if (n2 < NN) {
            float* hrow = h + (size_t)n2 * OD;
            unsigned short* hbrow = hxw + (size_t)n2 * 256 + 128;
            const int rb = row * 136;
#pragma unroll
            for (int jb = 0; jb < 2; ++jb) {
                int c = c0 + jb * 8;
                f16x8 Rv = *(const f16x8*)&LS[rb + c];
                f16x8 Zv = *(const f16x8*)&LS[8704 + rb + c];
                f16x8 Iv = *(const f16x8*)&LS[17408 + rb + c];
                f16x8 Hv = *(const f16x8*)&LS[26112 + rb + c];
                float4 h0 = *(const float4*)&hrow[c];
                float4 h1 = *(const float4*)&hrow[c + 4];
                float hold[8] = {h0.x, h0.y, h0.z, h0.w, h1.x, h1.y, h1.z, h1.w};
                float hn8[8];
                f16x8 hb8;
#pragma unroll
                for (int k = 0; k < 8; ++k) {
                    float R = (float)Rv[k], Z = (float)Zv[k];
                    float NV = tanhf((float)Iv[k] + R * (float)Hv[k]);
                    float v = (1.f - Z) * NV + Z * hold[k];
                    hn8[k] = v;
                    hb8[k] = (_Float16)v;
                }
                *(float4*)&hrow[c]     = make_float4(hn8[0], hn8[1], hn8[2], hn8[3]);
                *(float4*)&hrow[c + 4] = make_float4(hn8[4], hn8[5], hn8[6], hn8[7]);
                *(f16x8*)&hbrow[c] = hb8;
            }
        }
    }
}

// ---------------- graph readout: register acc over graph-sorted node list ------------
__global__ void k_readout(const float* __restrict__ h, const float* __restrict__ nf,
                          const int* __restrict__ nlist, const int* __restrict__ growp,
                          float* __restrict__ partial) {
    int g = blockIdx.x >> 3, c = blockIdx.x & (RC - 1);
    int d = threadIdx.x;
    int s = growp[g], e = growp[g + 1], len = e - s;
    int i0 = s + (int)((long long)len * c / RC);
    int i1 = s + (int)((long long)len * (c + 1) / RC);
    float acc = 0.f;
    for (int i = i0; i < i1; ++i) {
        int n = nlist[i];
        acc += (d < OD) ? h[(size_t)n * OD + d] : nf[(size_t)n * IND + (d - OD)];
    }
    partial[(size_t)blockIdx.x * 192 + d] = acc;
}

__global__ void k_reduce(const float* __restrict__ partial, float* __restrict__ feats) {
    int i = blockIdx.x * 256 + threadIdx.x;
    if (i >= NG * 192) return;
    int g = i / 192, d = i % 192;
    float s = 0.f;
    for (int c = 0; c < RC; ++c) s += partial[(size_t)(g * RC + c) * 192 + d];
    feats[i] = s;
}

__global__ void k_final(const float* __restrict__ feats, const float* __restrict__ W_cls,
                        const float* __restrict__ b_cls, float* __restrict__ out) {
    int g = threadIdx.x;
    if (g >= NG) return;
    float acc = b_cls[0];
    for (int d = 0; d < 192; ++d) acc += feats[g * 192 + d] * W_cls[d];
    out[g] = 1.f / (1.f + __expf(-acc));
}

extern "C" void kernel_launch(void* const* d_in, const int* in_sizes, int n_in,
                              void* d_out, int out_size, void* d_ws, size_t ws_size,
                              hipStream_t stream) {
    const float* nf    = (const float*)d_in[0];
    const int*   src   = (const int*)d_in[1];
    const int*   dst   = (const int*)d_in[2];
    const int*   et    = (const int*)d_in[3];
    const int*   gid   = (const int*)d_in[4];
    const float* Ws    = (const float*)d_in[5];
    const float* bs    = (const float*)d_in[6];
    const float* W_ih  = (const float*)d_in[7];
    const float* W_hh  = (const float*)d_in[8];
    const float* b_ih  = (const float*)d_in[9];
    const float* b_hh  = (const float*)d_in[10];
    const float* W_cls = (const float*)d_in[11];
    const float* b_cls = (const float*)d_in[12];
    float* out = (float*)d_out;

    char* ws = (char*)d_ws;
    size_t off = 0;
    auto alloc = [&](size_t bytes) -> void* {
        off = (off + 255) & ~(size_t)255;
        void* p = ws + off;
        off += bytes;
        return p;
    };
    float*          h    = (float*)alloc((size_t)NN * OD * 4);              // 25.6 MB
    unsigned short* hx   = (unsigned short*)alloc((size_t)NN * 256 * 2);    // 25.6 MB
    int*   deg4    = (int*)alloc((size_t)NN4 * 4);
    int*   rowp4   = (int*)alloc((size_t)(NN4 + 1) * 4);
    int*   cursor4 = (int*)alloc((size_t)NN4 * 4);
    int*   esrc    = (int*)alloc((size_t)NE * 4);
    int*   bsum    = (int*)alloc(256 * 4);
    int*   gdeg    = (int*)alloc(NG * 4);
    int*   growp   = (int*)alloc((NG + 1) * 4);
    int*   gcur    = (int*)alloc(NG * 4);
    int*   nlist   = (int*)alloc((size_t)NN * 4);
    float* feats   = (float*)alloc((size_t)NG * 192 * 4);
    float* partial = (float*)alloc((size_t)NG * RC * 192 * 4);              // 393 KB
    unsigned short* wsb = (unsigned short*)alloc((size_t)4 * 16384 * 2);
    unsigned short* Wpk = (unsigned short*)alloc((size_t)98304 * 2);
    float*          bpk = (float*)alloc(512 * 4);
    (void)ws_size; (void)in_sizes; (void)n_in; (void)out_size;

    hipMemsetAsync(deg4, 0, (size_t)NN4 * 4, stream);
    hipMemsetAsync(gdeg, 0, NG * 4, stream);

    k_cvt<<<(4 * 16384 + 255) / 256, 256, 0, stream>>>(Ws, wsb, 4 * 16384);
    k_pack<<<(98304 + 255) / 256, 256, 0, stream>>>(W_ih, W_hh, b_ih, b_hh, Wpk, bpk);

    k_init_h<<<(NN * OD + 255) / 256, 256, 0, stream>>>(nf, h, hx);

    // (dst, etype) CSR
    k_count<<<(NE + 255) / 256, 256, 0, stream>>>(dst, et, deg4);
    const int nb4 = (NN4 + 1023) / 1024;   // 196
    k_scan1<<<nb4, 1024, 0, stream>>>(deg4, rowp4, bsum, NN4);
    k_scan2<<<1, 256, 0, stream>>>(bsum, nb4);
    k_scan3<<<(NN4 + 255) / 256, 256, 0, stream>>>(deg4, bsum, rowp4, cursor4, NN4);
    k_fill<<<(NE + 255) / 256, 256, 0, stream>>>(src, dst, et, cursor4, esrc);

    // graph CSR (readout)
    const int nbn = (NN + 1023) / 1024;    // 49
    k_gcount<<<nbn, 1024, 0, stream>>>(gid, gdeg);
    k_gscan<<<1, NG, 0, stream>>>(gdeg, growp, gcur);
    k_gfill<<<nbn, 1024, 0, stream>>>(gid, gcur, nlist);

    const int mt64 = (NN + 63) / 64;   // 782 node tiles
    for (int s = 0; s < 8; ++s) {
        k_agg_gemm<<<mt64, 512, 0, stream>>>(hx, rowp4, esrc, deg4, wsb, bs, hx);
        k_gates_gru<<<mt64, 512, 0, stream>>>(hx, Wpk, bpk, h, hx);
    }

    k_readout<<<NG * RC, 192, 0, stream>>>(h, nf, nlist, growp, partial);
    k_reduce<<<(NG * 192 + 255) / 256, 256, 0, stream>>>(partial, feats);
    k_final<<<1, 64, 0, stream>>>(feats, W_cls, b_cls, out);
}